// Round 1
// 719.206 us; speedup vs baseline: 1.2713x; 1.2713x over previous
//
#include <hip/hip_runtime.h>
#include <cstdint>
#include <cstddef>

#define BT_TOT 64000
#define FIN    1024
#define GV     640
#define NV     320
#define VD     128
#define INV_BT (1.0f/64000.0f)

// K-tile = 16 (one k-chunk per 32x32x16 MFMA). 64 K-steps.
// Packed W tile (per kt): [s(hi/lo)][col 0..639][chunk 0..1][8 bf16] = 40960 B
#define WTILE_B 40960
// LDS per buffer: Ah 4096 | Al 4096 | B 40960  = 49152 B; double-buffered = 96 KB
#define BUF_B 49152

typedef __attribute__((ext_vector_type(8))) __bf16 bf16x8;
typedef __attribute__((ext_vector_type(16))) float f32x16;

typedef __attribute__((address_space(1))) void gvoid_t;
typedef __attribute__((address_space(3))) void lvoid_t;

__device__ inline short f2bf(float x) {            // RNE fp32 -> bf16 bits
    unsigned int u = __float_as_uint(x);
    unsigned int r = (u + 0x7fffu + ((u >> 16) & 1u)) >> 16;
    return (short)r;
}
__device__ inline float bf2f(short h) {
    return __uint_as_float(((unsigned int)(unsigned short)h) << 16);
}
__device__ inline bf16x8 ld_frag(const short* p) {
    union { uint4 u; bf16x8 v; } t;
    t.u = *(const uint4*)p;
    return t.v;
}
__device__ __forceinline__ void glds16(const void* g, void* l) {
    __builtin_amdgcn_global_load_lds((gvoid_t*)g, (lvoid_t*)l, 16, 0, 0);
}

// ---------- prep: split W into bf16 hi/lo, packed per-K-tile in LDS order ----------
// 320 blocks x 256 thr = 81920 threads; each handles one 8-elem k-chunk of one row.
__global__ __launch_bounds__(256) void prep(
    const float* __restrict__ W, char* __restrict__ Wpk,
    float* __restrict__ psum_g, int* __restrict__ cnt_g)
{
    const int t = blockIdx.x * 256 + threadIdx.x;
    if (t < GV) { psum_g[t] = 0.f; cnt_g[t] = 0; }
    const int r   = t >> 7;        // row 0..639
    const int ck8 = t & 127;       // which 8-elem chunk along k
    const int kt  = ck8 >> 1;      // K-tile 0..63
    const int ch  = ck8 & 1;       // chunk within tile (0/1)
    const float* src = W + (size_t)r * FIN + (size_t)ck8 * 8;
    const float4 a = ((const float4*)src)[0];
    const float4 b = ((const float4*)src)[1];
    float xs[8] = {a.x, a.y, a.z, a.w, b.x, b.y, b.z, b.w};
    short hi[8], lo[8];
#pragma unroll
    for (int e = 0; e < 8; ++e) {
        hi[e] = f2bf(xs[e]);
        lo[e] = f2bf(xs[e] - bf2f(hi[e]));
    }
    char* dst = Wpk + (size_t)kt * WTILE_B + (size_t)r * 32 + ch * 16;
    *(uint4*)dst             = *(uint4*)hi;   // s=0 (hi)
    *(uint4*)(dst + 20480)   = *(uint4*)lo;   // s=1 (lo)
}

// ---------- fused: 32x32x16 bf16-triple GEMM, 2-phase dbuf pipeline + epilogue ----------
// 500 blocks x 512 thr. Block = 128 rows x 640 cols. 8 waves: mw=wave&3 (32-row
// stripe), nw=wave>>2 (group, 320 cols). Wave tile 32x320 = 10 x (32x32), acc 160.
__global__ __launch_bounds__(512, 2) void fused(
    const float* __restrict__ X, const char* __restrict__ Wpk,
    const float* __restrict__ bias, const float* __restrict__ gumbel,
    const float* __restrict__ codebook, float* __restrict__ q,
    float* __restrict__ psum_g, int* __restrict__ cnt_g)
{
    __shared__ __align__(16) char smem[2 * BUF_B];   // 96 KB

    const int tid  = threadIdx.x;
    const int lane = tid & 63, wave = tid >> 6;
    const int mw = wave & 3, nw = wave >> 2;
    const int cl = lane & 31, h = lane >> 5;
    const int row0 = blockIdx.x * 128;

    // A staging role: thread -> row tid>>2 (0..127), 4-float k-chunk (tid&3)*4
    const int ar  = tid >> 2;
    const int akq = (tid & 3) * 4;

    f32x16 acc[10];
#pragma unroll
    for (int nt = 0; nt < 10; ++nt) acc[nt] = (f32x16)0.0f;

    // ---- prologue: stage K-tile 0 into buf0 ----
    {
#pragma unroll
        for (int i = 0; i < 5; ++i) {
            const int task = tid + 512 * i;
            glds16(Wpk + (size_t)task * 16, smem + 8192 + task * 16);
        }
        const float4 xa = *(const float4*)(X + (size_t)(row0 + ar) * FIN + akq);
        float xs[4] = {xa.x, xa.y, xa.z, xa.w};
        short hi4[4], lo4[4];
#pragma unroll
        for (int e = 0; e < 4; ++e) {
            hi4[e] = f2bf(xs[e]);
            lo4[e] = f2bf(xs[e] - bf2f(hi4[e]));
        }
        *(short4*)(smem + ar * 32 + akq * 2)        = make_short4(hi4[0], hi4[1], hi4[2], hi4[3]);
        *(short4*)(smem + 4096 + ar * 32 + akq * 2) = make_short4(lo4[0], lo4[1], lo4[2], lo4[3]);
    }
    __syncthreads();

    // ---- main loop: 64 K-steps, one barrier each, staging issued before MFMAs ----
    for (int t = 0; t < 64; ++t) {
        const int c = t & 1;
        char* bufc = smem + c * BUF_B;
        char* bufn = smem + (c ^ 1) * BUF_B;
        const bool more = (t < 63);
        float4 xa;
        if (more) {
            const char* wt = Wpk + (size_t)(t + 1) * WTILE_B;
#pragma unroll
            for (int i = 0; i < 5; ++i) {
                const int task = tid + 512 * i;
                glds16(wt + (size_t)task * 16, bufn + 8192 + task * 16);
            }
            xa = *(const float4*)(X + (size_t)(row0 + ar) * FIN + (t + 1) * 16 + akq);
        }

        __builtin_amdgcn_s_setprio(1);
        const int arow = mw * 32 + cl;
        const bf16x8 a_h = ld_frag((const short*)(bufc + arow * 32 + h * 16));
        const bf16x8 a_l = ld_frag((const short*)(bufc + 4096 + arow * 32 + h * 16));
#pragma unroll
        for (int nt = 0; nt < 10; ++nt) {
            const int bcol = nw * 320 + nt * 32 + cl;
            const bf16x8 b_h = ld_frag((const short*)(bufc + 8192 + bcol * 32 + h * 16));
            const bf16x8 b_l = ld_frag((const short*)(bufc + 8192 + 20480 + bcol * 32 + h * 16));
            acc[nt] = __builtin_amdgcn_mfma_f32_32x32x16_bf16(a_h, b_h, acc[nt], 0, 0, 0);
            acc[nt] = __builtin_amdgcn_mfma_f32_32x32x16_bf16(a_l, b_h, acc[nt], 0, 0, 0);
            acc[nt] = __builtin_amdgcn_mfma_f32_32x32x16_bf16(a_h, b_l, acc[nt], 0, 0, 0);
        }
        __builtin_amdgcn_s_setprio(0);

        if (more) {
            float xs[4] = {xa.x, xa.y, xa.z, xa.w};
            short hi4[4], lo4[4];
#pragma unroll
            for (int e = 0; e < 4; ++e) {
                hi4[e] = f2bf(xs[e]);
                lo4[e] = f2bf(xs[e] - bf2f(hi4[e]));
            }
            *(short4*)(bufn + ar * 32 + akq * 2)        = make_short4(hi4[0], hi4[1], hi4[2], hi4[3]);
            *(short4*)(bufn + 4096 + ar * 32 + akq * 2) = make_short4(lo4[0], lo4[1], lo4[2], lo4[3]);
        }
        __syncthreads();
    }

    // ---- epilogue (aliases buf0 A-region, safe after final barrier) ----
    float* psum_l = (float*)(smem);          // [640]
    int*   cnt_l  = (int*)(smem + 2560);     // [640]
    int*   gidx   = (int*)(smem + 5120);     // [128][2]

    for (int i = tid; i < GV; i += 512) { psum_l[i] = 0.f; cnt_l[i] = 0; }
    __syncthreads();

    // bias add (D layout 32x32: col = cl, row = (reg&3) + 8*(reg>>2) + 4*h)
#pragma unroll
    for (int nt = 0; nt < 10; ++nt) {
        const float bv = bias[nw * 320 + nt * 32 + cl];
#pragma unroll
        for (int r = 0; r < 16; ++r) acc[nt][r] += bv;
    }

    float pcol[10];
#pragma unroll
    for (int nt = 0; nt < 10; ++nt) pcol[nt] = 0.f;

#pragma unroll
    for (int reg = 0; reg < 16; ++reg) {
        const int rloc = mw * 32 + (reg & 3) + 8 * (reg >> 2) + 4 * h;
        const float* gp = gumbel + (size_t)(row0 + rloc) * GV + nw * 320;
        float bestv = -3.4e38f, gbv = -3.4e38f;
        int bestc = 0, gbc = 0;
#pragma unroll
        for (int nt = 0; nt < 10; ++nt) {
            const float v = acc[nt][reg];
            const int cc = nt * 32 + cl;
            const float tv = v + gp[cc];
            if (v > bestv) { bestv = v; bestc = cc; }
            if (tv > gbv)  { gbv = tv;  gbc = cc; }
        }
#pragma unroll
        for (int off = 1; off < 32; off <<= 1) {
            const float v2 = __shfl_xor(bestv, off); const int c2 = __shfl_xor(bestc, off);
            if (v2 > bestv || (v2 == bestv && c2 < bestc)) { bestv = v2; bestc = c2; }
            const float g2 = __shfl_xor(gbv, off); const int gc2 = __shfl_xor(gbc, off);
            if (g2 > gbv || (g2 == gbv && gc2 < gbc)) { gbv = g2; gbc = gc2; }
        }
        float e[10], s = 0.f;
#pragma unroll
        for (int nt = 0; nt < 10; ++nt) { e[nt] = __expf(acc[nt][reg] - bestv); s += e[nt]; }
#pragma unroll
        for (int off = 1; off < 32; off <<= 1) s += __shfl_xor(s, off);
        const float inv_s = 1.0f / s;
#pragma unroll
        for (int nt = 0; nt < 10; ++nt) pcol[nt] += e[nt] * inv_s;
        if (cl == 0) {
            atomicAdd(&cnt_l[nw * 320 + bestc], 1);
            gidx[rloc * 2 + nw] = nw * 320 + gbc;
        }
    }
#pragma unroll
    for (int nt = 0; nt < 10; ++nt) {
        const float v = pcol[nt] + __shfl_xor(pcol[nt], 32);
        if (h == 0) atomicAdd(&psum_l[nw * 320 + nt * 32 + cl], v);
    }
    __syncthreads();

    // q gather: 128 rows x 2 groups x 128 dims; 2 threads per (row,group)
    {
        const int unit = tid >> 1, half = tid & 1;
        const int row = unit >> 1, gq = unit & 1;
        const int idx = gidx[row * 2 + gq];
        const float4* srcp = (const float4*)(codebook + (size_t)idx * VD + half * 64);
        float4* dstp = (float4*)(q + (size_t)(row0 + row) * 256 + gq * VD + half * 64);
#pragma unroll
        for (int i = 0; i < 16; ++i) dstp[i] = srcp[i];
    }
    // flush block accumulators
    for (int i = tid; i < GV; i += 512) {
        atomicAdd(&psum_g[i], psum_l[i]);
        atomicAdd(&cnt_g[i], cnt_l[i]);
    }
}

// ---------- finalize ----------
__global__ void finalize(const int* __restrict__ cnt_g, const float* __restrict__ psum_g,
                         float* __restrict__ out_scalars)
{
    const int lane = threadIdx.x;   // 64 threads = 1 wave
    float hsum[2] = {0.f, 0.f}, p[2] = {0.f, 0.f};
    for (int i = lane; i < GV; i += 64) {
        const int g = i / NV;
        const float hp = (float)cnt_g[i] * INV_BT;
        const float ap = psum_g[i] * INV_BT;
        hsum[g] -= hp * logf(hp + 1e-7f);
        p[g]    -= ap * logf(ap + 1e-7f);
    }
#pragma unroll
    for (int off = 32; off > 0; off >>= 1) {
        hsum[0] += __shfl_xor(hsum[0], off); hsum[1] += __shfl_xor(hsum[1], off);
        p[0] += __shfl_xor(p[0], off);       p[1] += __shfl_xor(p[1], off);
    }
    if (lane == 0) {
        out_scalars[0] = expf(hsum[0]) + expf(hsum[1]);
        out_scalars[1] = expf(p[0]) + expf(p[1]);
    }
}

extern "C" void kernel_launch(void* const* d_in, const int* in_sizes, int n_in,
                              void* d_out, int out_size, void* d_ws, size_t ws_size,
                              hipStream_t stream)
{
    const float* X  = (const float*)d_in[0];   // [64000,1024]
    const float* W  = (const float*)d_in[1];   // [640,1024]
    const float* Bv = (const float*)d_in[2];   // [640]
    const float* CB = (const float*)d_in[3];   // [640,128]
    const float* GU = (const float*)d_in[4];   // [64000,640]

    float* q = (float*)d_out;                                  // [64000,256]
    float* out_scalars = (float*)d_out + (size_t)BT_TOT * 256; // 2 scalars

    char* ws = (char*)d_ws;
    float* psum_g = (float*)ws;                 // 640 floats
    int*   cnt_g  = (int*)(ws + 4096);          // 640 ints
    char*  Wpk    = ws + 8192;                  // 64 tiles * 40960 B = 2.62 MB

    prep<<<320, 256, 0, stream>>>(W, Wpk, psum_g, cnt_g);
    fused<<<500, 512, 0, stream>>>(X, Wpk, Bv, GU, CB, q, psum_g, cnt_g);
    finalize<<<1, 64, 0, stream>>>(cnt_g, psum_g, out_scalars);
}